// Round 7
// baseline (640.987 us; speedup 1.0000x reference)
//
#include <hip/hip_runtime.h>

// Fused entmax(alpha=1.3) attention, fp32. B=16, N=2048, D=64.
// R11: R10 with the attn-writeback bug fixed. R10's register-select
// writeback dropped support entries (lane L only knew its OWN compact
// elements but writes columns L*4..L*4+3 -> absmax 1.0). Restored R9's
// LDS prow scatter (zero-fill -> scatter -> vectorized nt-store readback),
// which is the cross-lane exchange that writeback needs. Kept from R10:
// packed (val|idx) cpk (LDS 40960 -> 4 blocks/CU), self-contained dense
// fallback (recomputes row from fp32 Q.K; s[] dead after compaction),
// bisect 8 + 2 Newton. Phase 1 unchanged (MFMA split-bf16 QK^T).

#define NBATCH 16
#define NSEQ   2048
#define DHEAD  64
#define OUT_OFF (NBATCH * NSEQ * DHEAD)   // out first, attn second
#define INV_A    3.3333333f               // 1/(alpha-1)
#define INV_A_M1 2.3333333f
#define IDXM 0x7FFu                       // 11-bit idx mask (NSEQ=2048)
#define VALM 0xFFFFF800u

typedef float  vfloat4 __attribute__((ext_vector_type(4)));
typedef float  f32x4   __attribute__((ext_vector_type(4)));
typedef short  bf16x8  __attribute__((ext_vector_type(8)));
typedef unsigned short u16x8 __attribute__((ext_vector_type(8)));

__device__ __forceinline__ float fast_log2(float x) { return __builtin_amdgcn_logf(x); }
__device__ __forceinline__ float fast_exp2(float x) { return __builtin_amdgcn_exp2f(x); }

__device__ __forceinline__ unsigned bf16_rne(float x) {
    const unsigned u = __float_as_uint(x);
    return (u + 0x7FFFu + ((u >> 16) & 1u)) >> 16;
}

// ---------- pre-kernel: split K into bf16 hi/lo planes in workspace ----------
__global__ __launch_bounds__(256) void ksplit_kernel(
    const float* __restrict__ K, unsigned short* __restrict__ Khi,
    unsigned short* __restrict__ Klo)
{
    const size_t idx = (size_t)blockIdx.x * 256 + threadIdx.x;  // float4 index
    const float4 x = ((const float4*)K)[idx];
    const float xs[4] = {x.x, x.y, x.z, x.w};
    unsigned short h[4], l[4];
    #pragma unroll
    for (int i = 0; i < 4; ++i) {
        const unsigned hr = bf16_rne(xs[i]);
        h[i] = (unsigned short)hr;
        l[i] = (unsigned short)bf16_rne(xs[i] - __uint_as_float(hr << 16));
    }
    ((ushort4*)Khi)[idx] = make_ushort4(h[0], h[1], h[2], h[3]);
    ((ushort4*)Klo)[idx] = make_ushort4(l[0], l[1], l[2], l[3]);
}

// ------------------------------ main kernel ---------------------------------
__global__ __launch_bounds__(512) void entmax_attn_kernel(
    const float* __restrict__ Q, const float* __restrict__ K,
    const float* __restrict__ V, float* __restrict__ Out,
    const unsigned short* __restrict__ Khi, const unsigned short* __restrict__ Klo)
{
    // reg0 (32 KB): phase1 staging (hi 16K | lo 16K bytes), then xbuf[16][512],
    //               then per-wave prow (1024 floats each).
    // cpk (8 KB): per wave 256 packed floats: row0[128], row1[128].
    __shared__ __align__(16) float reg0[8192];
    __shared__ __align__(16) float cpk[8 * 256];

    const int tid  = threadIdx.x;
    const int w    = tid >> 6;        // 0..7
    const int lane = tid & 63;
    const int arow = lane & 15;       // MFMA row / col lane index
    const int lg   = lane >> 4;       // lane group 0..3

    // XCD pinning: batch b -> XCD b%8
    const int i   = blockIdx.x;       // 0..2047
    const int xcd = i & 7;
    const int j2  = i >> 3;           // 0..255
    const int b   = xcd + 8 * (j2 & 1);
    const int rb  = j2 >> 1;          // 0..127
    const int n0  = rb * 16;          // 16 q-rows per block

    const float* Kb = K + (size_t)b * NSEQ * DHEAD;
    const float* Vb = V + (size_t)b * NSEQ * DHEAD;
    const unsigned short* KhiB = Khi + (size_t)b * NSEQ * DHEAD;
    const unsigned short* KloB = Klo + (size_t)b * NSEQ * DHEAD;
    char* ldsHi = (char*)reg0;
    char* ldsLo = (char*)reg0 + 16384;

    // ---- A fragments: Q rows in registers (scale 1/8 folded in) ----
    bf16x8 a_hi[2], a_lo[2];
    {
        const float* qrow = Q + ((size_t)b * NSEQ + (size_t)(n0 + arow)) * DHEAD;
        #pragma unroll
        for (int ks = 0; ks < 2; ++ks) {
            const int d0 = ks * 32 + lg * 8;
            const float4 x0 = *(const float4*)(qrow + d0);
            const float4 x1 = *(const float4*)(qrow + d0 + 4);
            const float xs[8] = {x0.x, x0.y, x0.z, x0.w, x1.x, x1.y, x1.z, x1.w};
            #pragma unroll
            for (int e = 0; e < 8; ++e) {
                const float xq = xs[e] * 0.125f;
                const unsigned hr = bf16_rne(xq);
                a_hi[ks][e] = (short)hr;
                a_lo[ks][e] = (short)bf16_rne(xq - __uint_as_float(hr << 16));
            }
        }
    }

    float s[2][32];
    const int kap = 16 * w + arow;          // this wave's key within a tile

    // ---- staging thread geometry ----
    const int keyA = tid >> 3, cA = tid & 7;
    const int keyB = keyA + 64;
    const size_t gA = (size_t)keyA * DHEAD + cA * 8;
    const size_t gB = (size_t)keyB * DHEAD + cA * 8;
    const int ofA = keyA * 128 + ((cA ^ (keyA & 7)) << 4);
    const int ofB = keyB * 128 + ((cA ^ (keyA & 7)) << 4);

    // prologue: prefetch tile 0 into regs
    u16x8 shA = *(const u16x8*)(KhiB + gA), slA = *(const u16x8*)(KloB + gA);
    u16x8 shB = *(const u16x8*)(KhiB + gB), slB = *(const u16x8*)(KloB + gB);

    // ---- 4 groups of 512 keys (4 tiles of 128); ALL STATIC ----
    #pragma unroll
    for (int g = 0; g < 4; ++g) {
        f32x4 acc[4];
        #pragma unroll
        for (int tt = 0; tt < 4; ++tt) acc[tt] = (f32x4){0.f, 0.f, 0.f, 0.f};

        #pragma unroll
        for (int tt = 0; tt < 4; ++tt) {
            const int t = 4 * g + tt;
            __syncthreads();
            *(u16x8*)(ldsHi + ofA) = shA;  *(u16x8*)(ldsLo + ofA) = slA;
            *(u16x8*)(ldsHi + ofB) = shB;  *(u16x8*)(ldsLo + ofB) = slB;
            __syncthreads();

            #pragma unroll
            for (int ks = 0; ks < 2; ++ks) {
                const int loff = kap * 128 + ((((ks << 2) | lg) ^ (kap & 7)) << 4);
                const bf16x8 bh = *(const bf16x8*)(ldsHi + loff);
                const bf16x8 bl = *(const bf16x8*)(ldsLo + loff);
                acc[tt] = __builtin_amdgcn_mfma_f32_16x16x32_bf16(a_hi[ks], bh, acc[tt], 0, 0, 0);
                acc[tt] = __builtin_amdgcn_mfma_f32_16x16x32_bf16(a_hi[ks], bl, acc[tt], 0, 0, 0);
                acc[tt] = __builtin_amdgcn_mfma_f32_16x16x32_bf16(a_lo[ks], bh, acc[tt], 0, 0, 0);
            }
            if (t < 15) {
                const size_t tb = (size_t)(t + 1) * (128 * DHEAD);
                shA = *(const u16x8*)(KhiB + tb + gA);
                slA = *(const u16x8*)(KloB + tb + gA);
                shB = *(const u16x8*)(KhiB + tb + gB);
                slB = *(const u16x8*)(KloB + tb + gB);
            }
        }

        // ---- exchange: C frags -> per-wave rows via xbuf[16][512] ----
        // C layout (m89): col(key-in-16) = lane&15, row = lg*4 + reg.
        __syncthreads();
        #pragma unroll
        for (int tt = 0; tt < 4; ++tt)
            #pragma unroll
            for (int i2 = 0; i2 < 4; ++i2)
                reg0[(lg * 4 + i2) * 512 + tt * 128 + kap] = acc[tt][i2];
        __syncthreads();
        #pragma unroll
        for (int r = 0; r < 2; ++r)
            #pragma unroll
            for (int jj = 0; jj < 8; ++jj)
                s[r][8 * g + jj] = reg0[(2 * w + r) * 512 + jj * 64 + lane];
    }
    __syncthreads();   // all xbuf reads done; reg0 becomes per-wave prow

    unsigned* pk0 = (unsigned*)(cpk + w * 256);
    unsigned* pk1 = pk0 + 128;
    float* prow = reg0 + w * 1024;
    const unsigned long long lt_mask = (1ull << lane) - 1ull;
    const int na = n0 + 2 * w;

    // ---- dual row max ----
    float mx0 = s[0][0], mx1 = s[1][0];
    #pragma unroll
    for (int j = 1; j < 32; ++j) { mx0 = fmaxf(mx0, s[0][j]); mx1 = fmaxf(mx1, s[1][j]); }
    #pragma unroll
    for (int off = 32; off >= 1; off >>= 1) {
        mx0 = fmaxf(mx0, __shfl_xor(mx0, off, 64));
        mx1 = fmaxf(mx1, __shfl_xor(mx1, off, 64));
    }

    // ---- dual ballot-compaction, packed (val | idx) ----
    int base0 = 0, base1 = 0;
    #pragma unroll
    for (int j = 0; j < 32; ++j) {
        const float v0 = s[0][j] - mx0;
        const float v1 = s[1][j] - mx1;
        const bool a0 = v0 > -1.0f;
        const bool a1 = v1 > -1.0f;
        const unsigned long long bm0 = __ballot(a0);
        const unsigned long long bm1 = __ballot(a1);
        const int q0 = base0 + __popcll(bm0 & lt_mask);
        const int q1 = base1 + __popcll(bm1 & lt_mask);
        const unsigned idx = (unsigned)(j * 64 + lane);
        if (a0 && q0 < 128) pk0[q0] = (__float_as_uint(v0) & VALM) | idx;
        if (a1 && q1 < 128) pk1[q1] = (__float_as_uint(v1) & VALM) | idx;
        base0 += __popcll(bm0);
        base1 += __popcll(bm1);
    }
    const int A0 = base0, A1 = base1;       // wave-uniform

    float* arow0 = Out + OUT_OFF + ((size_t)b * NSEQ + na) * NSEQ;
    float* arow1 = arow0 + NSEQ;

    if (A0 <= 128 && A1 <= 128) {
        // ================= dual sparse solver (common case) =================
        const unsigned u00 = pk0[lane],      u01 = pk0[64 + lane];
        const unsigned u10 = pk1[lane],      u11 = pk1[64 + lane];
        const float cv00 = __uint_as_float(u00 & VALM);
        const float cv01 = __uint_as_float(u01 & VALM);
        const float cv10 = __uint_as_float(u10 & VALM);
        const float cv11 = __uint_as_float(u11 & VALM);
        const bool ok00 = lane < A0, ok01 = 64 + lane < A0;
        const bool ok10 = lane < A1, ok11 = 64 + lane < A1;

        float lo0 = -1.0f, hi0 = -1e-6f, lo1 = -1.0f, hi1 = -1e-6f;
        #pragma unroll 1
        for (int it = 0; it < 8; ++it) {
            const float ta = 0.5f * (lo0 + hi0);
            const float tb = 0.5f * (lo1 + hi1);
            const float t00 = cv00 - ta, t01 = cv01 - ta;
            const float t10 = cv10 - tb, t11 = cv11 - tb;
            float S0 = ((ok00 && t00 > 0.f) ? fast_exp2(INV_A * fast_log2(t00)) : 0.f)
                     + ((ok01 && t01 > 0.f) ? fast_exp2(INV_A * fast_log2(t01)) : 0.f);
            float S1 = ((ok10 && t10 > 0.f) ? fast_exp2(INV_A * fast_log2(t10)) : 0.f)
                     + ((ok11 && t11 > 0.f) ? fast_exp2(INV_A * fast_log2(t11)) : 0.f);
            #pragma unroll
            for (int off = 32; off >= 1; off >>= 1) {
                S0 += __shfl_xor(S0, off, 64);
                S1 += __shfl_xor(S1, off, 64);
            }
            if (S0 > 1.f) lo0 = ta; else hi0 = ta;
            if (S1 > 1.f) lo1 = tb; else hi1 = tb;
        }
        float tau0 = lo0, tau1 = lo1;
        #pragma unroll 1
        for (int it = 0; it < 2; ++it) {
            const float t00 = cv00 - tau0, t01 = cv01 - tau0;
            const float t10 = cv10 - tau1, t11 = cv11 - tau1;
            float Sa0 = 0.f, Sb0 = 0.f, Sa1 = 0.f, Sb1 = 0.f;
            if (ok00 && t00 > 0.f) { const float l = fast_log2(t00); Sa0 += fast_exp2(INV_A * l); Sb0 += fast_exp2(INV_A_M1 * l); }
            if (ok01 && t01 > 0.f) { const float l = fast_log2(t01); Sa0 += fast_exp2(INV_A * l); Sb0 += fast_exp2(INV_A_M1 * l); }
            if (ok10 && t10 > 0.f) { const float l = fast_log2(t10); Sa1 += fast_exp2(INV_A * l); Sb1 += fast_exp2(INV_A_M1 * l); }
            if (ok11 && t11 > 0.f) { const float l = fast_log2(t11); Sa1 += fast_exp2(INV_A * l); Sb1 += fast_exp2(INV_A_M1 * l); }
            #pragma unroll
            for (int off = 32; off >= 1; off >>= 1) {
                Sa0 += __shfl_xor(Sa0, off, 64); Sb0 += __shfl_xor(Sb0, off, 64);
                Sa1 += __shfl_xor(Sa1, off, 64); Sb1 += __shfl_xor(Sb1, off, 64);
            }
            tau0 += (Sa0 - 1.f) / (INV_A * Sb0);
            tau0 = fmaxf(fminf(tau0, hi0), lo0);
            tau1 += (Sa1 - 1.f) / (INV_A * Sb1);
            tau1 = fmaxf(fminf(tau1, hi1), lo1);
        }

        // final p + dual normalize
        const float t00 = cv00 - tau0, t01 = cv01 - tau0;
        const float t10 = cv10 - tau1, t11 = cv11 - tau1;
        float p00 = (ok00 && t00 > 0.f) ? fast_exp2(INV_A * fast_log2(t00)) : 0.f;
        float p01 = (ok01 && t01 > 0.f) ? fast_exp2(INV_A * fast_log2(t01)) : 0.f;
        float p10 = (ok10 && t10 > 0.f) ? fast_exp2(INV_A * fast_log2(t10)) : 0.f;
        float p11 = (ok11 && t11 > 0.f) ? fast_exp2(INV_A * fast_log2(t11)) : 0.f;
        float S0 = p00 + p01, S1 = p10 + p11;
        #pragma unroll
        for (int off = 32; off >= 1; off >>= 1) {
            S0 += __shfl_xor(S0, off, 64);
            S1 += __shfl_xor(S1, off, 64);
        }
        const float rn0 = 1.f / (S0 + 1e-12f);
        const float rn1 = 1.f / (S1 + 1e-12f);
        p00 *= rn0; p01 *= rn0; p10 *= rn1; p11 *= rn1;
        const int i00 = ok00 ? (int)(u00 & IDXM) : -1;
        const int i01 = ok01 ? (int)(u01 & IDXM) : -1;
        const int i10 = ok10 ? (int)(u10 & IDXM) : -1;
        const int i11 = ok11 ? (int)(u11 & IDXM) : -1;
        // store packed normalized p back for the PV gather
        if (ok00) pk0[lane]      = (__float_as_uint(p00) & VALM) | (unsigned)i00;
        if (ok01) pk0[64 + lane] = (__float_as_uint(p01) & VALM) | (unsigned)i01;
        if (ok10) pk1[lane]      = (__float_as_uint(p10) & VALM) | (unsigned)i10;
        if (ok11) pk1[64 + lane] = (__float_as_uint(p11) & VALM) | (unsigned)i11;

        // ---- attn rows: LDS prow scatter (cross-lane) + vectorized nt-store
        #pragma unroll
        for (int seg = 0; seg < 2; ++seg) {
            #pragma unroll
            for (int z = 0; z < 4; ++z)
                *(float4*)&prow[(z * 64 + lane) * 4] = make_float4(0.f, 0.f, 0.f, 0.f);
            if (ok00 && (i00 >> 10) == seg) prow[i00 & 1023] = p00;
            if (ok01 && (i01 >> 10) == seg) prow[i01 & 1023] = p01;
            #pragma unroll
            for (int z = 0; z < 4; ++z) {
                const vfloat4 pv = *(const vfloat4*)&prow[(z * 64 + lane) * 4];
                __builtin_nontemporal_store(pv,
                    (vfloat4*)&arow0[seg * 1024 + (z * 64 + lane) * 4]);
            }
        }
        #pragma unroll
        for (int seg = 0; seg < 2; ++seg) {
            #pragma unroll
            for (int z = 0; z < 4; ++z)
                *(float4*)&prow[(z * 64 + lane) * 4] = make_float4(0.f, 0.f, 0.f, 0.f);
            if (ok10 && (i10 >> 10) == seg) prow[i10 & 1023] = p10;
            if (ok11 && (i11 >> 10) == seg) prow[i11 & 1023] = p11;
            #pragma unroll
            for (int z = 0; z < 4; ++z) {
                const vfloat4 pv = *(const vfloat4*)&prow[(z * 64 + lane) * 4];
                __builtin_nontemporal_store(pv,
                    (vfloat4*)&arow1[seg * 1024 + (z * 64 + lane) * 4]);
            }
        }

        // ---- sparse PV: packed loads, unroll 8 ----
        float out0 = 0.f, out1 = 0.f;
        int ii = 0;
        #pragma unroll 1
        for (; ii + 8 <= A0; ii += 8) {
            const unsigned ua = pk0[ii+0], ub = pk0[ii+1], uc = pk0[ii+2], ud = pk0[ii+3];
            const unsigned ue = pk0[ii+4], uf = pk0[ii+5], ug = pk0[ii+6], uh = pk0[ii+7];
            out0 += __uint_as_float(ua & VALM) * Vb[(size_t)(ua & IDXM) * DHEAD + lane]
                  + __uint_as_float(ub & VALM) * Vb[(size_t)(ub & IDXM) * DHEAD + lane]
                  + __uint_as_float(uc & VALM) * Vb[(size_t)(uc & IDXM) * DHEAD + lane]
                  + __uint_as_float(ud & VALM) * Vb[(size_t)(ud & IDXM) * DHEAD + lane]
                  + __uint_as_float(ue & VALM) * Vb[(size_t)(ue & IDXM) * DHEAD + lane]
                  + __uint_as_float(uf & VALM) * Vb[(size_t)(uf & IDXM) * DHEAD + lane]
                  + __uint_as_float(ug & VALM) * Vb[(size_t)(ug & IDXM) * DHEAD + lane]
                  + __uint_as_float(uh & VALM) * Vb[(size_t)(uh & IDXM) * DHEAD + lane];
        }
        #pragma unroll 1
        for (; ii < A0; ++ii) {
            const unsigned ua = pk0[ii];
            out0 += __uint_as_float(ua & VALM) * Vb[(size_t)(ua & IDXM) * DHEAD + lane];
        }
        int jj = 0;
        #pragma unroll 1
        for (; jj + 8 <= A1; jj += 8) {
            const unsigned ua = pk1[jj+0], ub = pk1[jj+1], uc = pk1[jj+2], ud = pk1[jj+3];
            const unsigned ue = pk1[jj+4], uf = pk1[jj+5], ug = pk1[jj+6], uh = pk1[jj+7];
            out1 += __uint_as_float(ua & VALM) * Vb[(size_t)(ua & IDXM) * DHEAD + lane]
                  + __uint_as_float(ub & VALM) * Vb[(size_t)(ub & IDXM) * DHEAD + lane]
                  + __uint_as_float(uc & VALM) * Vb[(size_t)(uc & IDXM) * DHEAD + lane]
                  + __uint_as_float(ud & VALM) * Vb[(size_t)(ud & IDXM) * DHEAD + lane]
                  + __uint_as_float(ue & VALM) * Vb[(size_t)(ue & IDXM) * DHEAD + lane]
                  + __uint_as_float(uf & VALM) * Vb[(size_t)(uf & IDXM) * DHEAD + lane]
                  + __uint_as_float(ug & VALM) * Vb[(size_t)(ug & IDXM) * DHEAD + lane]
                  + __uint_as_float(uh & VALM) * Vb[(size_t)(uh & IDXM) * DHEAD + lane];
        }
        #pragma unroll 1
        for (; jj < A1; ++jj) {
            const unsigned ua = pk1[jj];
            out1 += __uint_as_float(ua & VALM) * Vb[(size_t)(ua & IDXM) * DHEAD + lane];
        }

        Out[((size_t)b * NSEQ + na) * DHEAD + lane] = out0;
        Out[((size_t)b * NSEQ + na + 1) * DHEAD + lane] = out1;
    } else {
        // ============ fallback: per-row (rare; correctness only) ============
        #pragma unroll 1
        for (int r = 0; r < 2; ++r) {
            const int A = r ? A1 : A0;
            unsigned* pk = r ? pk1 : pk0;
            float* arowX = r ? arow1 : arow0;
            float outacc = 0.f;

            if (A <= 128) {
                // single-row sparse solver on packed set
                const unsigned u0 = pk[lane], u1 = pk[64 + lane];
                const float cv0 = __uint_as_float(u0 & VALM);
                const float cv1 = __uint_as_float(u1 & VALM);
                const bool ok0 = (lane < A);
                const bool ok1 = (64 + lane < A);

                float lo = -1.0f, hi = -1e-6f;
                #pragma unroll 1
                for (int it = 0; it < 10; ++it) {
                    const float tau = 0.5f * (lo + hi);
                    const float t0 = cv0 - tau, t1 = cv1 - tau;
                    float S = ((ok0 && t0 > 0.f) ? fast_exp2(INV_A * fast_log2(t0)) : 0.f)
                            + ((ok1 && t1 > 0.f) ? fast_exp2(INV_A * fast_log2(t1)) : 0.f);
                    #pragma unroll
                    for (int off = 32; off >= 1; off >>= 1) S += __shfl_xor(S, off, 64);
                    if (S > 1.f) lo = tau; else hi = tau;
                }
                float tau = lo;
                #pragma unroll 1
                for (int it = 0; it < 2; ++it) {
                    const float t0 = cv0 - tau, t1 = cv1 - tau;
                    float S1 = 0.f, S2 = 0.f;
                    if (ok0 && t0 > 0.f) { const float l = fast_log2(t0); S1 += fast_exp2(INV_A * l); S2 += fast_exp2(INV_A_M1 * l); }
                    if (ok1 && t1 > 0.f) { const float l = fast_log2(t1); S1 += fast_exp2(INV_A * l); S2 += fast_exp2(INV_A_M1 * l); }
                    #pragma unroll
                    for (int off = 32; off >= 1; off >>= 1) {
                        S1 += __shfl_xor(S1, off, 64);
                        S2 += __shfl_xor(S2, off, 64);
                    }
                    tau += (S1 - 1.f) / (INV_A * S2);
                    tau = fmaxf(fminf(tau, hi), lo);
                }
                const float t0 = cv0 - tau, t1 = cv1 - tau;
                float p0 = (ok0 && t0 > 0.f) ? fast_exp2(INV_A * fast_log2(t0)) : 0.f;
                float p1 = (ok1 && t1 > 0.f) ? fast_exp2(INV_A * fast_log2(t1)) : 0.f;
                float S = p0 + p1;
                #pragma unroll
                for (int off = 32; off >= 1; off >>= 1) S += __shfl_xor(S, off, 64);
                const float rnorm = 1.f / (S + 1e-12f);
                p0 *= rnorm; p1 *= rnorm;
                const int i0 = ok0 ? (int)(u0 & IDXM) : -1;
                const int i1 = ok1 ? (int)(u1 & IDXM) : -1;
                if (ok0) pk[lane]      = (__float_as_uint(p0) & VALM) | (unsigned)i0;
                if (ok1) pk[64 + lane] = (__float_as_uint(p1) & VALM) | (unsigned)i1;

                // LDS prow scatter writeback (cross-lane correct)
                #pragma unroll
                for (int seg = 0; seg < 2; ++seg) {
                    #pragma unroll
                    for (int z = 0; z < 4; ++z)
                        *(float4*)&prow[(z * 64 + lane) * 4] = make_float4(0.f, 0.f, 0.f, 0.f);
                    if (ok0 && (i0 >> 10) == seg) prow[i0 & 1023] = p0;
                    if (ok1 && (i1 >> 10) == seg) prow[i1 & 1023] = p1;
                    #pragma unroll
                    for (int z = 0; z < 4; ++z) {
                        const vfloat4 pv = *(const vfloat4*)&prow[(z * 64 + lane) * 4];
                        __builtin_nontemporal_store(pv,
                            (vfloat4*)&arowX[seg * 1024 + (z * 64 + lane) * 4]);
                    }
                }

                int ii = 0;
                #pragma unroll 1
                for (; ii + 4 <= A; ii += 4) {
                    const unsigned ua = pk[ii+0], ub = pk[ii+1], uc = pk[ii+2], ud = pk[ii+3];
                    outacc += __uint_as_float(ua & VALM) * Vb[(size_t)(ua & IDXM) * DHEAD + lane]
                            + __uint_as_float(ub & VALM) * Vb[(size_t)(ub & IDXM) * DHEAD + lane]
                            + __uint_as_float(uc & VALM) * Vb[(size_t)(uc & IDXM) * DHEAD + lane]
                            + __uint_as_float(ud & VALM) * Vb[(size_t)(ud & IDXM) * DHEAD + lane];
                }
                #pragma unroll 1
                for (; ii < A; ++ii) {
                    const unsigned ua = pk[ii];
                    outacc += __uint_as_float(ua & VALM) * Vb[(size_t)(ua & IDXM) * DHEAD + lane];
                }
            } else {
                // dense: recompute this row's scores exactly from fp32 Q.K
                const float* qr = Q + ((size_t)b * NSEQ + (size_t)(na + r)) * DHEAD;
                float xd[32];
                #pragma unroll 1
                for (int j = 0; j < 32; ++j) {
                    const float* kr = Kb + (size_t)(j * 64 + lane) * DHEAD;
                    float d = 0.f;
                    #pragma unroll
                    for (int c = 0; c < 16; ++c) {
                        const float4 qa = ((const float4*)qr)[c];
                        const float4 ka = ((const float4*)kr)[c];
                        d += qa.x*ka.x + qa.y*ka.y + qa.z*ka.z + qa.w*ka.w;
                    }
                    xd[j] = d * 0.125f;
                }
                float mxe = xd[0];
                #pragma unroll
                for (int j = 1; j < 32; ++j) mxe = fmaxf(mxe, xd[j]);
                #pragma unroll
                for (int off = 32; off >= 1; off >>= 1) mxe = fmaxf(mxe, __shfl_xor(mxe, off, 64));
                #pragma unroll
                for (int j = 0; j < 32; ++j) xd[j] -= mxe;

                float lo = -1.0f, hi = -1e-6f;
                #pragma unroll 1
                for (int it = 0; it < 12; ++it) {
                    const float tau = 0.5f * (lo + hi);
                    float S = 0.f;
                    #pragma unroll
                    for (int j = 0; j < 32; ++j) {
                        const float t = xd[j] - tau;
                        const float p = fast_exp2(INV_A * fast_log2(t));
                        S += (t > 0.f) ? p : 0.f;
                    }
                    #pragma unroll
                    for (int off = 32; off >= 1; off >>= 1) S += __shfl_xor(S, off, 64);
                    if (S > 1.f) lo = tau; else hi = tau;
                }
                float tau = lo;
                #pragma unroll 1
                for (int it = 0; it < 2; ++it) {
                    float S1 = 0.f, S2 = 0.f;
                    #pragma unroll
                    for (int j = 0; j < 32; ++j) {
                        const float t = xd[j] - tau;
                        if (t > 0.f) {
                            const float l = fast_log2(t);
                            S1 += fast_exp2(INV_A * l); S2 += fast_exp2(INV_A_M1 * l);
                        }
                    }
                    #pragma unroll
                    for (int off = 32; off >= 1; off >>= 1) {
                        S1 += __shfl_xor(S1, off, 64);
                        S2 += __shfl_xor(S2, off, 64);
                    }
                    tau += (S1 - 1.f) / (INV_A * S2);
                    tau = fmaxf(fminf(tau, hi), lo);
                }
                float S = 0.f;
                float pd[32];
                #pragma unroll
                for (int j = 0; j < 32; ++j) {
                    const float t = xd[j] - tau;
                    const float p = (t > 0.f) ? fast_exp2(INV_A * fast_log2(t)) : 0.f;
                    pd[j] = p;
                    S += p;
                }
                #pragma unroll
                for (int off = 32; off >= 1; off >>= 1) S += __shfl_xor(S, off, 64);
                const float rnorm = 1.f / (S + 1e-12f);
                #pragma unroll
                for (int j = 0; j < 32; ++j) {
                    pd[j] *= rnorm;
                    __builtin_nontemporal_store(pd[j], &arowX[j * 64 + lane]);
                }
                // dense PV via shfl broadcast (race-free, cold path)
                #pragma unroll 1
                for (int j = 0; j < 32; ++j) {
                    #pragma unroll 1
                    for (int l = 0; l < 64; ++l) {
                        const float pv = __shfl(pd[j], l, 64);
                        outacc += pv * Vb[(size_t)(j * 64 + l) * DHEAD + lane];
                    }
                }
            }

            Out[((size_t)b * NSEQ + (na + r)) * DHEAD + lane] = outacc;
        }
    }
}

extern "C" void kernel_launch(void* const* d_in, const int* in_sizes, int n_in,
                              void* d_out, int out_size, void* d_ws, size_t ws_size,
                              hipStream_t stream) {
    const float* q = (const float*)d_in[0];
    const float* k = (const float*)d_in[1];
    const float* v = (const float*)d_in[2];
    float* out = (float*)d_out;
    (void)in_sizes; (void)n_in; (void)out_size; (void)ws_size;

    unsigned short* Khi = (unsigned short*)d_ws;                       // 4 MB
    unsigned short* Klo = Khi + (size_t)NBATCH * NSEQ * DHEAD;         // +4 MB

    hipLaunchKernelGGL(ksplit_kernel, dim3(2048), dim3(256), 0, stream, k, Khi, Klo);
    hipLaunchKernelGGL(entmax_attn_kernel, dim3(2048), dim3(512), 0, stream,
                       q, k, v, out, Khi, Klo);
}

// Round 8
// 482.153 us; speedup vs baseline: 1.3294x; 1.3294x over previous
//
#include <hip/hip_runtime.h>

// Fused entmax(alpha=1.3) attention, fp32. B=16, N=2048, D=64.
// R12: R11 minus the register bomb. R11's "exact fp32 recompute" dense
// fallback carried xd[32]+pd[32] (64 live floats in one branch) -> kernel
// VGPR 52->128 -> occupancy 29->11% -> 230->417us. Dense fallback reverted
// to R9's register-lean form: uses the MFMA scores s[r][j]-mx (static
// indices, AGPR-friendly; bf16-split accuracy is fine for this ~never-taken
// path), p staged through prow segments. Fallback r-loop fully unrolled
// (rule #20). Kept from R10/R11: packed (val|idx) cpk -> LDS 40960 (4
// blocks/CU), bisect 8 + 2 Newton, prow scatter writeback (cross-lane).

#define NBATCH 16
#define NSEQ   2048
#define DHEAD  64
#define OUT_OFF (NBATCH * NSEQ * DHEAD)   // out first, attn second
#define INV_A    3.3333333f               // 1/(alpha-1)
#define INV_A_M1 2.3333333f
#define IDXM 0x7FFu                       // 11-bit idx mask (NSEQ=2048)
#define VALM 0xFFFFF800u

typedef float  vfloat4 __attribute__((ext_vector_type(4)));
typedef float  f32x4   __attribute__((ext_vector_type(4)));
typedef short  bf16x8  __attribute__((ext_vector_type(8)));
typedef unsigned short u16x8 __attribute__((ext_vector_type(8)));

__device__ __forceinline__ float fast_log2(float x) { return __builtin_amdgcn_logf(x); }
__device__ __forceinline__ float fast_exp2(float x) { return __builtin_amdgcn_exp2f(x); }

__device__ __forceinline__ unsigned bf16_rne(float x) {
    const unsigned u = __float_as_uint(x);
    return (u + 0x7FFFu + ((u >> 16) & 1u)) >> 16;
}

// ---------- pre-kernel: split K into bf16 hi/lo planes in workspace ----------
__global__ __launch_bounds__(256) void ksplit_kernel(
    const float* __restrict__ K, unsigned short* __restrict__ Khi,
    unsigned short* __restrict__ Klo)
{
    const size_t idx = (size_t)blockIdx.x * 256 + threadIdx.x;  // float4 index
    const float4 x = ((const float4*)K)[idx];
    const float xs[4] = {x.x, x.y, x.z, x.w};
    unsigned short h[4], l[4];
    #pragma unroll
    for (int i = 0; i < 4; ++i) {
        const unsigned hr = bf16_rne(xs[i]);
        h[i] = (unsigned short)hr;
        l[i] = (unsigned short)bf16_rne(xs[i] - __uint_as_float(hr << 16));
    }
    ((ushort4*)Khi)[idx] = make_ushort4(h[0], h[1], h[2], h[3]);
    ((ushort4*)Klo)[idx] = make_ushort4(l[0], l[1], l[2], l[3]);
}

// ------------------------------ main kernel ---------------------------------
__global__ __launch_bounds__(512) void entmax_attn_kernel(
    const float* __restrict__ Q, const float* __restrict__ V,
    float* __restrict__ Out,
    const unsigned short* __restrict__ Khi, const unsigned short* __restrict__ Klo)
{
    // reg0 (32 KB): phase1 staging (hi 16K | lo 16K bytes), then xbuf[16][512],
    //               then per-wave prow (1024 floats each).
    // cpk (8 KB): per wave 256 packed floats: row0[128], row1[128].
    __shared__ __align__(16) float reg0[8192];
    __shared__ __align__(16) float cpk[8 * 256];

    const int tid  = threadIdx.x;
    const int w    = tid >> 6;        // 0..7
    const int lane = tid & 63;
    const int arow = lane & 15;       // MFMA row / col lane index
    const int lg   = lane >> 4;       // lane group 0..3

    // XCD pinning: batch b -> XCD b%8
    const int i   = blockIdx.x;       // 0..2047
    const int xcd = i & 7;
    const int j2  = i >> 3;           // 0..255
    const int b   = xcd + 8 * (j2 & 1);
    const int rb  = j2 >> 1;          // 0..127
    const int n0  = rb * 16;          // 16 q-rows per block

    const float* Vb = V + (size_t)b * NSEQ * DHEAD;
    const unsigned short* KhiB = Khi + (size_t)b * NSEQ * DHEAD;
    const unsigned short* KloB = Klo + (size_t)b * NSEQ * DHEAD;
    char* ldsHi = (char*)reg0;
    char* ldsLo = (char*)reg0 + 16384;

    // ---- A fragments: Q rows in registers (scale 1/8 folded in) ----
    bf16x8 a_hi[2], a_lo[2];
    {
        const float* qrow = Q + ((size_t)b * NSEQ + (size_t)(n0 + arow)) * DHEAD;
        #pragma unroll
        for (int ks = 0; ks < 2; ++ks) {
            const int d0 = ks * 32 + lg * 8;
            const float4 x0 = *(const float4*)(qrow + d0);
            const float4 x1 = *(const float4*)(qrow + d0 + 4);
            const float xs[8] = {x0.x, x0.y, x0.z, x0.w, x1.x, x1.y, x1.z, x1.w};
            #pragma unroll
            for (int e = 0; e < 8; ++e) {
                const float xq = xs[e] * 0.125f;
                const unsigned hr = bf16_rne(xq);
                a_hi[ks][e] = (short)hr;
                a_lo[ks][e] = (short)bf16_rne(xq - __uint_as_float(hr << 16));
            }
        }
    }

    float s[2][32];
    const int kap = 16 * w + arow;          // this wave's key within a tile

    // ---- staging thread geometry ----
    const int keyA = tid >> 3, cA = tid & 7;
    const int keyB = keyA + 64;
    const size_t gA = (size_t)keyA * DHEAD + cA * 8;
    const size_t gB = (size_t)keyB * DHEAD + cA * 8;
    const int ofA = keyA * 128 + ((cA ^ (keyA & 7)) << 4);
    const int ofB = keyB * 128 + ((cA ^ (keyA & 7)) << 4);

    // prologue: prefetch tile 0 into regs
    u16x8 shA = *(const u16x8*)(KhiB + gA), slA = *(const u16x8*)(KloB + gA);
    u16x8 shB = *(const u16x8*)(KhiB + gB), slB = *(const u16x8*)(KloB + gB);

    // ---- 4 groups of 512 keys (4 tiles of 128); ALL STATIC ----
    #pragma unroll
    for (int g = 0; g < 4; ++g) {
        f32x4 acc[4];
        #pragma unroll
        for (int tt = 0; tt < 4; ++tt) acc[tt] = (f32x4){0.f, 0.f, 0.f, 0.f};

        #pragma unroll
        for (int tt = 0; tt < 4; ++tt) {
            const int t = 4 * g + tt;
            __syncthreads();
            *(u16x8*)(ldsHi + ofA) = shA;  *(u16x8*)(ldsLo + ofA) = slA;
            *(u16x8*)(ldsHi + ofB) = shB;  *(u16x8*)(ldsLo + ofB) = slB;
            __syncthreads();

            #pragma unroll
            for (int ks = 0; ks < 2; ++ks) {
                const int loff = kap * 128 + ((((ks << 2) | lg) ^ (kap & 7)) << 4);
                const bf16x8 bh = *(const bf16x8*)(ldsHi + loff);
                const bf16x8 bl = *(const bf16x8*)(ldsLo + loff);
                acc[tt] = __builtin_amdgcn_mfma_f32_16x16x32_bf16(a_hi[ks], bh, acc[tt], 0, 0, 0);
                acc[tt] = __builtin_amdgcn_mfma_f32_16x16x32_bf16(a_hi[ks], bl, acc[tt], 0, 0, 0);
                acc[tt] = __builtin_amdgcn_mfma_f32_16x16x32_bf16(a_lo[ks], bh, acc[tt], 0, 0, 0);
            }
            if (t < 15) {
                const size_t tb = (size_t)(t + 1) * (128 * DHEAD);
                shA = *(const u16x8*)(KhiB + tb + gA);
                slA = *(const u16x8*)(KloB + tb + gA);
                shB = *(const u16x8*)(KhiB + tb + gB);
                slB = *(const u16x8*)(KloB + tb + gB);
            }
        }

        // ---- exchange: C frags -> per-wave rows via xbuf[16][512] ----
        // C layout (m89): col(key-in-16) = lane&15, row = lg*4 + reg.
        __syncthreads();
        #pragma unroll
        for (int tt = 0; tt < 4; ++tt)
            #pragma unroll
            for (int i2 = 0; i2 < 4; ++i2)
                reg0[(lg * 4 + i2) * 512 + tt * 128 + kap] = acc[tt][i2];
        __syncthreads();
        #pragma unroll
        for (int r = 0; r < 2; ++r)
            #pragma unroll
            for (int jj = 0; jj < 8; ++jj)
                s[r][8 * g + jj] = reg0[(2 * w + r) * 512 + jj * 64 + lane];
    }
    __syncthreads();   // all xbuf reads done; reg0 becomes per-wave prow

    unsigned* pk0 = (unsigned*)(cpk + w * 256);
    unsigned* pk1 = pk0 + 128;
    float* prow = reg0 + w * 1024;
    const unsigned long long lt_mask = (1ull << lane) - 1ull;
    const int na = n0 + 2 * w;

    // ---- dual row max ----
    float mx0 = s[0][0], mx1 = s[1][0];
    #pragma unroll
    for (int j = 1; j < 32; ++j) { mx0 = fmaxf(mx0, s[0][j]); mx1 = fmaxf(mx1, s[1][j]); }
    #pragma unroll
    for (int off = 32; off >= 1; off >>= 1) {
        mx0 = fmaxf(mx0, __shfl_xor(mx0, off, 64));
        mx1 = fmaxf(mx1, __shfl_xor(mx1, off, 64));
    }

    // ---- dual ballot-compaction, packed (val | idx) ----
    int base0 = 0, base1 = 0;
    #pragma unroll
    for (int j = 0; j < 32; ++j) {
        const float v0 = s[0][j] - mx0;
        const float v1 = s[1][j] - mx1;
        const bool a0 = v0 > -1.0f;
        const bool a1 = v1 > -1.0f;
        const unsigned long long bm0 = __ballot(a0);
        const unsigned long long bm1 = __ballot(a1);
        const int q0 = base0 + __popcll(bm0 & lt_mask);
        const int q1 = base1 + __popcll(bm1 & lt_mask);
        const unsigned idx = (unsigned)(j * 64 + lane);
        if (a0 && q0 < 128) pk0[q0] = (__float_as_uint(v0) & VALM) | idx;
        if (a1 && q1 < 128) pk1[q1] = (__float_as_uint(v1) & VALM) | idx;
        base0 += __popcll(bm0);
        base1 += __popcll(bm1);
    }
    const int A0 = base0, A1 = base1;       // wave-uniform

    float* arow0 = Out + OUT_OFF + ((size_t)b * NSEQ + na) * NSEQ;
    float* arow1 = arow0 + NSEQ;

    if (A0 <= 128 && A1 <= 128) {
        // ================= dual sparse solver (common case) =================
        const unsigned u00 = pk0[lane],      u01 = pk0[64 + lane];
        const unsigned u10 = pk1[lane],      u11 = pk1[64 + lane];
        const float cv00 = __uint_as_float(u00 & VALM);
        const float cv01 = __uint_as_float(u01 & VALM);
        const float cv10 = __uint_as_float(u10 & VALM);
        const float cv11 = __uint_as_float(u11 & VALM);
        const bool ok00 = lane < A0, ok01 = 64 + lane < A0;
        const bool ok10 = lane < A1, ok11 = 64 + lane < A1;

        float lo0 = -1.0f, hi0 = -1e-6f, lo1 = -1.0f, hi1 = -1e-6f;
        #pragma unroll 1
        for (int it = 0; it < 8; ++it) {
            const float ta = 0.5f * (lo0 + hi0);
            const float tb = 0.5f * (lo1 + hi1);
            const float t00 = cv00 - ta, t01 = cv01 - ta;
            const float t10 = cv10 - tb, t11 = cv11 - tb;
            float S0 = ((ok00 && t00 > 0.f) ? fast_exp2(INV_A * fast_log2(t00)) : 0.f)
                     + ((ok01 && t01 > 0.f) ? fast_exp2(INV_A * fast_log2(t01)) : 0.f);
            float S1 = ((ok10 && t10 > 0.f) ? fast_exp2(INV_A * fast_log2(t10)) : 0.f)
                     + ((ok11 && t11 > 0.f) ? fast_exp2(INV_A * fast_log2(t11)) : 0.f);
            #pragma unroll
            for (int off = 32; off >= 1; off >>= 1) {
                S0 += __shfl_xor(S0, off, 64);
                S1 += __shfl_xor(S1, off, 64);
            }
            if (S0 > 1.f) lo0 = ta; else hi0 = ta;
            if (S1 > 1.f) lo1 = tb; else hi1 = tb;
        }
        float tau0 = lo0, tau1 = lo1;
        #pragma unroll 1
        for (int it = 0; it < 2; ++it) {
            const float t00 = cv00 - tau0, t01 = cv01 - tau0;
            const float t10 = cv10 - tau1, t11 = cv11 - tau1;
            float Sa0 = 0.f, Sb0 = 0.f, Sa1 = 0.f, Sb1 = 0.f;
            if (ok00 && t00 > 0.f) { const float l = fast_log2(t00); Sa0 += fast_exp2(INV_A * l); Sb0 += fast_exp2(INV_A_M1 * l); }
            if (ok01 && t01 > 0.f) { const float l = fast_log2(t01); Sa0 += fast_exp2(INV_A * l); Sb0 += fast_exp2(INV_A_M1 * l); }
            if (ok10 && t10 > 0.f) { const float l = fast_log2(t10); Sa1 += fast_exp2(INV_A * l); Sb1 += fast_exp2(INV_A_M1 * l); }
            if (ok11 && t11 > 0.f) { const float l = fast_log2(t11); Sa1 += fast_exp2(INV_A * l); Sb1 += fast_exp2(INV_A_M1 * l); }
            #pragma unroll
            for (int off = 32; off >= 1; off >>= 1) {
                Sa0 += __shfl_xor(Sa0, off, 64); Sb0 += __shfl_xor(Sb0, off, 64);
                Sa1 += __shfl_xor(Sa1, off, 64); Sb1 += __shfl_xor(Sb1, off, 64);
            }
            tau0 += (Sa0 - 1.f) / (INV_A * Sb0);
            tau0 = fmaxf(fminf(tau0, hi0), lo0);
            tau1 += (Sa1 - 1.f) / (INV_A * Sb1);
            tau1 = fmaxf(fminf(tau1, hi1), lo1);
        }

        // final p + dual normalize
        const float t00 = cv00 - tau0, t01 = cv01 - tau0;
        const float t10 = cv10 - tau1, t11 = cv11 - tau1;
        float p00 = (ok00 && t00 > 0.f) ? fast_exp2(INV_A * fast_log2(t00)) : 0.f;
        float p01 = (ok01 && t01 > 0.f) ? fast_exp2(INV_A * fast_log2(t01)) : 0.f;
        float p10 = (ok10 && t10 > 0.f) ? fast_exp2(INV_A * fast_log2(t10)) : 0.f;
        float p11 = (ok11 && t11 > 0.f) ? fast_exp2(INV_A * fast_log2(t11)) : 0.f;
        float S0 = p00 + p01, S1 = p10 + p11;
        #pragma unroll
        for (int off = 32; off >= 1; off >>= 1) {
            S0 += __shfl_xor(S0, off, 64);
            S1 += __shfl_xor(S1, off, 64);
        }
        const float rn0 = 1.f / (S0 + 1e-12f);
        const float rn1 = 1.f / (S1 + 1e-12f);
        p00 *= rn0; p01 *= rn0; p10 *= rn1; p11 *= rn1;
        const int i00 = ok00 ? (int)(u00 & IDXM) : -1;
        const int i01 = ok01 ? (int)(u01 & IDXM) : -1;
        const int i10 = ok10 ? (int)(u10 & IDXM) : -1;
        const int i11 = ok11 ? (int)(u11 & IDXM) : -1;
        // store packed normalized p back for the PV gather
        if (ok00) pk0[lane]      = (__float_as_uint(p00) & VALM) | (unsigned)i00;
        if (ok01) pk0[64 + lane] = (__float_as_uint(p01) & VALM) | (unsigned)i01;
        if (ok10) pk1[lane]      = (__float_as_uint(p10) & VALM) | (unsigned)i10;
        if (ok11) pk1[64 + lane] = (__float_as_uint(p11) & VALM) | (unsigned)i11;

        // ---- attn rows: LDS prow scatter (cross-lane) + vectorized nt-store
        #pragma unroll
        for (int seg = 0; seg < 2; ++seg) {
            #pragma unroll
            for (int z = 0; z < 4; ++z)
                *(float4*)&prow[(z * 64 + lane) * 4] = make_float4(0.f, 0.f, 0.f, 0.f);
            if (ok00 && (i00 >> 10) == seg) prow[i00 & 1023] = p00;
            if (ok01 && (i01 >> 10) == seg) prow[i01 & 1023] = p01;
            #pragma unroll
            for (int z = 0; z < 4; ++z) {
                const vfloat4 pv = *(const vfloat4*)&prow[(z * 64 + lane) * 4];
                __builtin_nontemporal_store(pv,
                    (vfloat4*)&arow0[seg * 1024 + (z * 64 + lane) * 4]);
            }
        }
        #pragma unroll
        for (int seg = 0; seg < 2; ++seg) {
            #pragma unroll
            for (int z = 0; z < 4; ++z)
                *(float4*)&prow[(z * 64 + lane) * 4] = make_float4(0.f, 0.f, 0.f, 0.f);
            if (ok10 && (i10 >> 10) == seg) prow[i10 & 1023] = p10;
            if (ok11 && (i11 >> 10) == seg) prow[i11 & 1023] = p11;
            #pragma unroll
            for (int z = 0; z < 4; ++z) {
                const vfloat4 pv = *(const vfloat4*)&prow[(z * 64 + lane) * 4];
                __builtin_nontemporal_store(pv,
                    (vfloat4*)&arow1[seg * 1024 + (z * 64 + lane) * 4]);
            }
        }

        // ---- sparse PV: packed loads, unroll 8 ----
        float out0 = 0.f, out1 = 0.f;
        int ii = 0;
        #pragma unroll 1
        for (; ii + 8 <= A0; ii += 8) {
            const unsigned ua = pk0[ii+0], ub = pk0[ii+1], uc = pk0[ii+2], ud = pk0[ii+3];
            const unsigned ue = pk0[ii+4], uf = pk0[ii+5], ug = pk0[ii+6], uh = pk0[ii+7];
            out0 += __uint_as_float(ua & VALM) * Vb[(size_t)(ua & IDXM) * DHEAD + lane]
                  + __uint_as_float(ub & VALM) * Vb[(size_t)(ub & IDXM) * DHEAD + lane]
                  + __uint_as_float(uc & VALM) * Vb[(size_t)(uc & IDXM) * DHEAD + lane]
                  + __uint_as_float(ud & VALM) * Vb[(size_t)(ud & IDXM) * DHEAD + lane]
                  + __uint_as_float(ue & VALM) * Vb[(size_t)(ue & IDXM) * DHEAD + lane]
                  + __uint_as_float(uf & VALM) * Vb[(size_t)(uf & IDXM) * DHEAD + lane]
                  + __uint_as_float(ug & VALM) * Vb[(size_t)(ug & IDXM) * DHEAD + lane]
                  + __uint_as_float(uh & VALM) * Vb[(size_t)(uh & IDXM) * DHEAD + lane];
        }
        #pragma unroll 1
        for (; ii < A0; ++ii) {
            const unsigned ua = pk0[ii];
            out0 += __uint_as_float(ua & VALM) * Vb[(size_t)(ua & IDXM) * DHEAD + lane];
        }
        int jj = 0;
        #pragma unroll 1
        for (; jj + 8 <= A1; jj += 8) {
            const unsigned ua = pk1[jj+0], ub = pk1[jj+1], uc = pk1[jj+2], ud = pk1[jj+3];
            const unsigned ue = pk1[jj+4], uf = pk1[jj+5], ug = pk1[jj+6], uh = pk1[jj+7];
            out1 += __uint_as_float(ua & VALM) * Vb[(size_t)(ua & IDXM) * DHEAD + lane]
                  + __uint_as_float(ub & VALM) * Vb[(size_t)(ub & IDXM) * DHEAD + lane]
                  + __uint_as_float(uc & VALM) * Vb[(size_t)(uc & IDXM) * DHEAD + lane]
                  + __uint_as_float(ud & VALM) * Vb[(size_t)(ud & IDXM) * DHEAD + lane]
                  + __uint_as_float(ue & VALM) * Vb[(size_t)(ue & IDXM) * DHEAD + lane]
                  + __uint_as_float(uf & VALM) * Vb[(size_t)(uf & IDXM) * DHEAD + lane]
                  + __uint_as_float(ug & VALM) * Vb[(size_t)(ug & IDXM) * DHEAD + lane]
                  + __uint_as_float(uh & VALM) * Vb[(size_t)(uh & IDXM) * DHEAD + lane];
        }
        #pragma unroll 1
        for (; jj < A1; ++jj) {
            const unsigned ua = pk1[jj];
            out1 += __uint_as_float(ua & VALM) * Vb[(size_t)(ua & IDXM) * DHEAD + lane];
        }

        Out[((size_t)b * NSEQ + na) * DHEAD + lane] = out0;
        Out[((size_t)b * NSEQ + na + 1) * DHEAD + lane] = out1;
    } else {
        // ============ fallback: per-row (rare; correctness only) ============
        #pragma unroll
        for (int r = 0; r < 2; ++r) {
            const int A = r ? A1 : A0;
            const float mxr = r ? mx1 : mx0;
            unsigned* pk = r ? pk1 : pk0;
            float* arowX = r ? arow1 : arow0;
            float outacc = 0.f;

            if (A <= 128) {
                // single-row sparse solver on packed set
                const unsigned u0 = pk[lane], u1 = pk[64 + lane];
                const float cv0 = __uint_as_float(u0 & VALM);
                const float cv1 = __uint_as_float(u1 & VALM);
                const bool ok0 = (lane < A);
                const bool ok1 = (64 + lane < A);

                float lo = -1.0f, hi = -1e-6f;
                #pragma unroll 1
                for (int it = 0; it < 10; ++it) {
                    const float tau = 0.5f * (lo + hi);
                    const float t0 = cv0 - tau, t1 = cv1 - tau;
                    float S = ((ok0 && t0 > 0.f) ? fast_exp2(INV_A * fast_log2(t0)) : 0.f)
                            + ((ok1 && t1 > 0.f) ? fast_exp2(INV_A * fast_log2(t1)) : 0.f);
                    #pragma unroll
                    for (int off = 32; off >= 1; off >>= 1) S += __shfl_xor(S, off, 64);
                    if (S > 1.f) lo = tau; else hi = tau;
                }
                float tau = lo;
                #pragma unroll 1
                for (int it = 0; it < 2; ++it) {
                    const float t0 = cv0 - tau, t1 = cv1 - tau;
                    float S1 = 0.f, S2 = 0.f;
                    if (ok0 && t0 > 0.f) { const float l = fast_log2(t0); S1 += fast_exp2(INV_A * l); S2 += fast_exp2(INV_A_M1 * l); }
                    if (ok1 && t1 > 0.f) { const float l = fast_log2(t1); S1 += fast_exp2(INV_A * l); S2 += fast_exp2(INV_A_M1 * l); }
                    #pragma unroll
                    for (int off = 32; off >= 1; off >>= 1) {
                        S1 += __shfl_xor(S1, off, 64);
                        S2 += __shfl_xor(S2, off, 64);
                    }
                    tau += (S1 - 1.f) / (INV_A * S2);
                    tau = fmaxf(fminf(tau, hi), lo);
                }
                const float t0 = cv0 - tau, t1 = cv1 - tau;
                float p0 = (ok0 && t0 > 0.f) ? fast_exp2(INV_A * fast_log2(t0)) : 0.f;
                float p1 = (ok1 && t1 > 0.f) ? fast_exp2(INV_A * fast_log2(t1)) : 0.f;
                float S = p0 + p1;
                #pragma unroll
                for (int off = 32; off >= 1; off >>= 1) S += __shfl_xor(S, off, 64);
                const float rnorm = 1.f / (S + 1e-12f);
                p0 *= rnorm; p1 *= rnorm;
                const int i0 = ok0 ? (int)(u0 & IDXM) : -1;
                const int i1 = ok1 ? (int)(u1 & IDXM) : -1;
                if (ok0) pk[lane]      = (__float_as_uint(p0) & VALM) | (unsigned)i0;
                if (ok1) pk[64 + lane] = (__float_as_uint(p1) & VALM) | (unsigned)i1;

                // LDS prow scatter writeback (cross-lane correct)
                #pragma unroll
                for (int seg = 0; seg < 2; ++seg) {
                    #pragma unroll
                    for (int z = 0; z < 4; ++z)
                        *(float4*)&prow[(z * 64 + lane) * 4] = make_float4(0.f, 0.f, 0.f, 0.f);
                    if (ok0 && (i0 >> 10) == seg) prow[i0 & 1023] = p0;
                    if (ok1 && (i1 >> 10) == seg) prow[i1 & 1023] = p1;
                    #pragma unroll
                    for (int z = 0; z < 4; ++z) {
                        const vfloat4 pv = *(const vfloat4*)&prow[(z * 64 + lane) * 4];
                        __builtin_nontemporal_store(pv,
                            (vfloat4*)&arowX[seg * 1024 + (z * 64 + lane) * 4]);
                    }
                }

                int ii = 0;
                #pragma unroll 1
                for (; ii + 4 <= A; ii += 4) {
                    const unsigned ua = pk[ii+0], ub = pk[ii+1], uc = pk[ii+2], ud = pk[ii+3];
                    outacc += __uint_as_float(ua & VALM) * Vb[(size_t)(ua & IDXM) * DHEAD + lane]
                            + __uint_as_float(ub & VALM) * Vb[(size_t)(ub & IDXM) * DHEAD + lane]
                            + __uint_as_float(uc & VALM) * Vb[(size_t)(uc & IDXM) * DHEAD + lane]
                            + __uint_as_float(ud & VALM) * Vb[(size_t)(ud & IDXM) * DHEAD + lane];
                }
                #pragma unroll 1
                for (; ii < A; ++ii) {
                    const unsigned ua = pk[ii];
                    outacc += __uint_as_float(ua & VALM) * Vb[(size_t)(ua & IDXM) * DHEAD + lane];
                }
            } else {
                // dense fallback on MFMA scores (register-lean; ~never taken)
                float lo = -1.0f, hi = -1e-6f;
                #pragma unroll 1
                for (int it = 0; it < 12; ++it) {
                    const float tau = 0.5f * (lo + hi);
                    float S = 0.f;
                    #pragma unroll
                    for (int j = 0; j < 32; ++j) {
                        const float t = s[r][j] - mxr - tau;
                        const float p = fast_exp2(INV_A * fast_log2(t));
                        S += (t > 0.f) ? p : 0.f;
                    }
                    #pragma unroll
                    for (int off = 32; off >= 1; off >>= 1) S += __shfl_xor(S, off, 64);
                    if (S > 1.f) lo = tau; else hi = tau;
                }
                float tau = lo;
                #pragma unroll 1
                for (int it = 0; it < 2; ++it) {
                    float S1 = 0.f, S2 = 0.f;
                    #pragma unroll
                    for (int j = 0; j < 32; ++j) {
                        const float t = s[r][j] - mxr - tau;
                        if (t > 0.f) {
                            const float l = fast_log2(t);
                            S1 += fast_exp2(INV_A * l); S2 += fast_exp2(INV_A_M1 * l);
                        }
                    }
                    #pragma unroll
                    for (int off = 32; off >= 1; off >>= 1) {
                        S1 += __shfl_xor(S1, off, 64);
                        S2 += __shfl_xor(S2, off, 64);
                    }
                    tau += (S1 - 1.f) / (INV_A * S2);
                    tau = fmaxf(fminf(tau, hi), lo);
                }
                float S = 0.f;
                #pragma unroll
                for (int j = 0; j < 32; ++j) {
                    const float t = s[r][j] - mxr - tau;
                    const float p = (t > 0.f) ? fast_exp2(INV_A * fast_log2(t)) : 0.f;
                    s[r][j] = p;
                    S += p;
                }
                #pragma unroll
                for (int off = 32; off >= 1; off >>= 1) S += __shfl_xor(S, off, 64);
                const float rnorm = 1.f / (S + 1e-12f);

                #pragma unroll
                for (int seg = 0; seg < 2; ++seg) {
                    #pragma unroll
                    for (int jj = 0; jj < 16; ++jj)
                        prow[jj * 64 + lane] = s[r][seg * 16 + jj] * rnorm;
                    #pragma unroll
                    for (int z = 0; z < 16; ++z)
                        __builtin_nontemporal_store(prow[z * 64 + lane],
                                                    &arowX[seg * 1024 + z * 64 + lane]);
                    #pragma unroll 4
                    for (int m = 0; m < 1024; ++m)
                        outacc += prow[m] * Vb[(size_t)(seg * 1024 + m) * DHEAD + lane];
                }
            }

            Out[((size_t)b * NSEQ + (na + r)) * DHEAD + lane] = outacc;
        }
    }
}

extern "C" void kernel_launch(void* const* d_in, const int* in_sizes, int n_in,
                              void* d_out, int out_size, void* d_ws, size_t ws_size,
                              hipStream_t stream) {
    const float* q = (const float*)d_in[0];
    const float* k = (const float*)d_in[1];
    const float* v = (const float*)d_in[2];
    float* out = (float*)d_out;
    (void)in_sizes; (void)n_in; (void)out_size; (void)ws_size;

    unsigned short* Khi = (unsigned short*)d_ws;                       // 4 MB
    unsigned short* Klo = Khi + (size_t)NBATCH * NSEQ * DHEAD;         // +4 MB

    hipLaunchKernelGGL(ksplit_kernel, dim3(2048), dim3(256), 0, stream, k, Khi, Klo);
    hipLaunchKernelGGL(entmax_attn_kernel, dim3(2048), dim3(512), 0, stream,
                       q, v, out, Khi, Klo);
}